// Round 7
// baseline (413.836 us; speedup 1.0000x reference)
//
#include <hip/hip_runtime.h>

#define NPTS 65536
#define KC   1024
#define DD   512

using bf16x8 = __attribute__((ext_vector_type(8))) __bf16;
using f32x4  = __attribute__((ext_vector_type(4))) float;

// pack float4 -> 4 bf16 (truncation)
__device__ __forceinline__ uint2 pack4(const float4& v) {
  uint2 r;
  r.x = (__float_as_uint(v.x) >> 16) | (__float_as_uint(v.y) & 0xffff0000u);
  r.y = (__float_as_uint(v.z) >> 16) | (__float_as_uint(v.w) & 0xffff0000u);
  return r;
}

// ---------------- c2[k] = ||center_k||^2 (exact fp32) ----------------
__global__ __launch_bounds__(256) void c2_kernel(const float* __restrict__ centers,
                                                 float* __restrict__ c2) {
  int row = (blockIdx.x * 256 + threadIdx.x) >> 6;
  int lane = threadIdx.x & 63;
  const float4* c4 = (const float4*)(centers + (size_t)row * DD);
  float s = 0.f;
#pragma unroll
  for (int j = 0; j < 2; j++) {
    float4 v = c4[lane + 64 * j];
    s += v.x * v.x + v.y * v.y + v.z * v.z + v.w * v.w;
  }
#pragma unroll
  for (int off = 32; off; off >>= 1) s += __shfl_down(s, off, 64);
  if (lane == 0) c2[row] = s;
}

// ---------------- fused: convert + MFMA argmin + loss ----------------
// 512 threads = 8 waves (2m x 4n of 64x64 tiles).  BM=128, BN=256, BK=64.
// fp32 loaded from global, packed to bf16 in-register, staged to LDS with the
// conflict-free slot formula slot(r,oct) = r*8 + (oct ^ (r&7)).
// loss = sum(x2) + sum_m(c2[y[m]] - 2*dot(x_m, c_y[m])), captured in the fold.
__global__ __launch_bounds__(512, 2) void fused_kernel(
    const float* __restrict__ x, const float* __restrict__ centers,
    const float* __restrict__ c2g, const int* __restrict__ y,
    float* __restrict__ ynew_out, float* __restrict__ ploss) {
  __shared__ uint4 As[1024];    // 128 rows x 8 octs (16 KB)
  __shared__ uint4 Bs[2048];    // 256 rows x 8 octs (32 KB)
  __shared__ float c2s[1024];
  __shared__ int   ys[128];
  __shared__ float vS[4][128];
  __shared__ int   iS[4][128];
  __shared__ float lred[8];

  const int t = threadIdx.x;           // 0..511
  const int w = t >> 6, l = t & 63;
  const int wm = w >> 2, wn = w & 3;   // wave tile: rows wm*64+, cols wn*64+
  const int q4 = l >> 4, m16 = l & 15;
  const int row0 = blockIdx.x * 128;

  c2s[t] = c2g[t];
  c2s[t + 512] = c2g[t + 512];
  if (t < 128) ys[t] = y[row0 + t];
  __syncthreads();

  int ysv[16];
#pragma unroll
  for (int i = 0; i < 4; i++)
#pragma unroll
    for (int r = 0; r < 4; r++)
      ysv[i * 4 + r] = ys[wm * 64 + i * 16 + q4 * 4 + r];

  // A staging: thread -> row t>>2 (0..127), octs {ja, ja+4}, ja = t&3
  const int ra_s = t >> 2, ja = t & 3;
  const float4* ag = (const float4*)x + (size_t)(row0 + ra_s) * 128;
  const int aslot0 = ra_s * 8 + (ja ^ (ra_s & 7));
  const int aslot1 = ra_s * 8 + ((ja + 4) ^ (ra_s & 7));
  const int abase = ja * 2;

  // B staging: thread -> row t>>1 (0..255), octs jb4..jb4+3, jb4 = (t&1)*4
  const int rb_s = t >> 1, jb4 = (t & 1) * 4;
  int bslot[4];
#pragma unroll
  for (int jj = 0; jj < 4; jj++)
    bslot[jj] = rb_s * 8 + ((jb4 + jj) ^ (rb_s & 7));
  const int bbase = jb4 * 2;

  float best[16];
  int bi_[16];
#pragma unroll
  for (int i = 0; i < 16; i++) { best[i] = 3.4e38f; bi_[i] = 0; }
  float lsum = 0.f, x2s = 0.f;

  for (int n0 = 0; n0 < KC; n0 += 256) {
    f32x4 acc[4][4];
#pragma unroll
    for (int i = 0; i < 4; i++)
#pragma unroll
      for (int j = 0; j < 4; j++) acc[i][j] = (f32x4){0.f, 0.f, 0.f, 0.f};

    const float4* bg = (const float4*)centers + (size_t)(n0 + rb_s) * 128;

    for (int ks = 0; ks < 8; ks++) {
      // global fp32 loads (L2-hot after first pass) + in-register bf16 pack
      const int ab = ks * 16 + abase;
      float4 a0 = ag[ab], a1 = ag[ab + 1], a2 = ag[ab + 8], a3 = ag[ab + 9];
      const int bb = ks * 16 + bbase;
      float4 b[8];
#pragma unroll
      for (int jj = 0; jj < 8; jj++) b[jj] = bg[bb + jj];
      if (n0 == 0) {  // exact fp32 x2 accumulation (once per element)
        x2s += a0.x * a0.x + a0.y * a0.y + a0.z * a0.z + a0.w * a0.w;
        x2s += a1.x * a1.x + a1.y * a1.y + a1.z * a1.z + a1.w * a1.w;
        x2s += a2.x * a2.x + a2.y * a2.y + a2.z * a2.z + a2.w * a2.w;
        x2s += a3.x * a3.x + a3.y * a3.y + a3.z * a3.z + a3.w * a3.w;
      }
      uint2 pa0 = pack4(a0), pa1 = pack4(a1), pa2 = pack4(a2), pa3 = pack4(a3);
      uint2 pb[8];
#pragma unroll
      for (int jj = 0; jj < 8; jj++) pb[jj] = pack4(b[jj]);
      __syncthreads();  // previous window's fragment reads complete
      As[aslot0] = make_uint4(pa0.x, pa0.y, pa1.x, pa1.y);
      As[aslot1] = make_uint4(pa2.x, pa2.y, pa3.x, pa3.y);
#pragma unroll
      for (int jj = 0; jj < 4; jj++)
        Bs[bslot[jj]] = make_uint4(pb[2 * jj].x, pb[2 * jj].y,
                                   pb[2 * jj + 1].x, pb[2 * jj + 1].y);
      __syncthreads();  // staging complete
#pragma unroll
      for (int kk = 0; kk < 2; kk++) {
        const int oct = kk * 4 + q4;
        bf16x8 af[4];
#pragma unroll
        for (int i = 0; i < 4; i++) {
          const int ra = wm * 64 + i * 16 + m16;
          af[i] = *(const bf16x8*)&As[ra * 8 + (oct ^ (m16 & 7))];
        }
#pragma unroll
        for (int j = 0; j < 4; j++) {
          const int rb = wn * 64 + j * 16 + m16;
          bf16x8 bf = *(const bf16x8*)&Bs[rb * 8 + (oct ^ (m16 & 7))];
#pragma unroll
          for (int i = 0; i < 4; i++)
            acc[i][j] = __builtin_amdgcn_mfma_f32_16x16x32_bf16(af[i], bf, acc[i][j], 0, 0, 0);
        }
      }
    }

    // fold: argmin + loss capture.  C/D: col=lane&15, row=(lane>>4)*4+reg
#pragma unroll
    for (int j = 0; j < 4; j++) {
      const int n = n0 + wn * 64 + j * 16 + m16;
      const float cc = c2s[n];
#pragma unroll
      for (int i = 0; i < 4; i++)
#pragma unroll
        for (int r = 0; r < 4; r++) {
          float v = fmaf(-2.f, acc[i][j][r], cc);
          const int bi = i * 4 + r;
          if (n == ysv[bi]) lsum += v;
          if (v < best[bi]) { best[bi] = v; bi_[bi] = n; }
        }
    }
  }

  // per-wave reduce across the 16 m16 lanes sharing each row, then stage
  // per-wave winners to LDS for the cross-wave (wn) reduce.
#pragma unroll
  for (int bi = 0; bi < 16; bi++) {
    float v = best[bi];
    int idx = bi_[bi];
#pragma unroll
    for (int off = 8; off; off >>= 1) {
      float ov = __shfl_xor(v, off, 64);
      int oi = __shfl_xor(idx, off, 64);
      if (ov < v || (ov == v && oi < idx)) { v = ov; idx = oi; }
    }
    if (m16 == 0) {
      const int r64 = (bi >> 2) * 16 + q4 * 4 + (bi & 3);
      vS[wn][wm * 64 + r64] = v;
      iS[wn][wm * 64 + r64] = idx;
    }
  }
  __syncthreads();
  if (t < 128) {
    float v = vS[0][t];
    int idx = iS[0][t];
#pragma unroll
    for (int k = 1; k < 4; k++) {
      float ov = vS[k][t];
      int oi = iS[k][t];
      if (ov < v || (ov == v && oi < idx)) { v = ov; idx = oi; }
    }
    ynew_out[row0 + t] = (float)idx;
  }

  // loss partial: bf16 dot terms + exact x2
  lsum += x2s;
#pragma unroll
  for (int off = 32; off; off >>= 1) lsum += __shfl_down(lsum, off, 64);
  if (l == 0) lred[w] = lsum;
  __syncthreads();
  if (t == 0) {
    float s = 0.f;
#pragma unroll
    for (int k = 0; k < 8; k++) s += lred[k];
    ploss[blockIdx.x] = s;
  }
}

// out[0] = sum(ploss[512])
__global__ __launch_bounds__(256) void loss_final(const float* __restrict__ ploss,
                                                  float* __restrict__ out) {
  float s = ploss[threadIdx.x] + ploss[threadIdx.x + 256];
#pragma unroll
  for (int off = 32; off; off >>= 1) s += __shfl_down(s, off, 64);
  __shared__ float ps[4];
  if ((threadIdx.x & 63) == 0) ps[threadIdx.x >> 6] = s;
  __syncthreads();
  if (threadIdx.x == 0) out[0] = ps[0] + ps[1] + ps[2] + ps[3];
}

// ================= launcher =================

extern "C" void kernel_launch(void* const* d_in, const int* in_sizes, int n_in,
                              void* d_out, int out_size, void* d_ws, size_t ws_size,
                              hipStream_t stream) {
  const float* x       = (const float*)d_in[0];
  const int*   y       = (const int*)d_in[1];
  const float* centers = (const float*)d_in[2];
  float* out = (float*)d_out;  // out[0] = loss, out[1..] = ynew as float

  float* c2    = (float*)d_ws;  // KC floats
  float* ploss = c2 + KC;       // 512 floats   (ws need: 6 KB; observed >=68 MB)

  c2_kernel<<<KC / 4, 256, 0, stream>>>(centers, c2);
  fused_kernel<<<NPTS / 128, 512, 0, stream>>>(x, centers, c2, y, out + 1, ploss);
  loss_final<<<1, 256, 0, stream>>>(ploss, out);
}